// Round 6
// baseline (373.725 us; speedup 1.0000x reference)
//
#include <hip/hip_runtime.h>
#include <hip/hip_bf16.h>

typedef short bf16x8 __attribute__((ext_vector_type(8)));
typedef float f32x4 __attribute__((ext_vector_type(4)));
typedef unsigned int u32x4 __attribute__((ext_vector_type(4)));

#define MFMA(a, b, c) __builtin_amdgcn_mfma_f32_16x16x32_bf16((a), (b), (c), 0, 0, 0)

__device__ __forceinline__ unsigned short f2bf(float f) {
    unsigned u = __builtin_bit_cast(unsigned, f);
    unsigned r = u + 0x7FFFu + ((u >> 16) & 1u);   // RNE
    return (unsigned short)(r >> 16);
}

// pair of f32 -> packed bf16 dword (v_cvt_pk_bf16_f32)
__device__ __forceinline__ unsigned pk_bf16(float lo, float hi) {
    __hip_bfloat162 p = __float22bfloat162_rn(make_float2(lo, hi));
    unsigned r;
    __builtin_memcpy(&r, &p, sizeof(r));
    return r;
}

__device__ __forceinline__ float sigm(float x) {
    float e = __builtin_amdgcn_exp2f(-1.44269504088896f * x);
    return __builtin_amdgcn_rcpf(1.0f + e);
}

// Two waves per group of 16 batches; wave w owns h-units 16w..16w+15.
// Lane l: batch n = l&15, q = l>>4; computes units 16w+4q+r (r=0..3).
// Per-wave k-map: B/A elems 0-3 <-> OWN units (16w+4q+j), elems 4-7 <-> partner
// units (16(1-w)+4q+(j-4)). Both waves assemble B = {own, oth} with zero selects
// (dot products invariant under consistent k-relabeling; validated R1).
// Weights pre-scaled: i,f,o rows by -log2(e); g rows by +2*log2(e).
// Cell state scaled: c' = 2*log2(e)*c.
// Pipeline: own-half recurrent MFMA issued pre-barrier; partner-half post-read,
// covered by the independent x-projection MFMAs.
__global__ __launch_bounds__(128, 2) void lstm_mfma6_kernel(
    const float* __restrict__ x,     // [B,512,3]
    const float* __restrict__ W_ih,  // [128,3]
    const float* __restrict__ W_hh,  // [128,32]
    const float* __restrict__ b_ih,  // [128]
    const float* __restrict__ b_hh,  // [128]
    const float* __restrict__ W_fc,  // [32]
    const float* __restrict__ b_fc,  // [1]
    float* __restrict__ out)         // [B]
{
    const int lane = threadIdx.x & 63;
    const int w    = threadIdx.x >> 6;
    const int ow   = 1 - w;
    const int n    = lane & 15;
    const int q    = lane >> 4;
    const int group = blockIdx.x;

    __shared__ uint2 hx[2][2][64];   // [buf][wave-half][lane]: 8B lane-linear, conflict-free
    __shared__ float fcp[2][16];

    const float NL2E  = -1.4426950408889634f;  // -log2(e)
    const float P2L2E =  2.8853900817779268f;  // +2*log2(e)

    // A fragments: 4 gate tiles (G=0..3 = i,f,g,o), rows 32G + 16w + n.
    bf16x8 A_hh[4], A_x[4];
#pragma unroll
    for (int G = 0; G < 4; ++G) {
        const int g = 32 * G + 16 * w + n;
        const float s = (G == 2) ? P2L2E : NL2E;
        bf16x8 a, ax;
#pragma unroll
        for (int j = 0; j < 8; ++j) {
            const int col = (j < 4) ? (16 * w + 4 * q + j) : (16 * ow + 4 * q + (j - 4));
            a[j] = (short)f2bf(s * W_hh[g * 32 + col]);
            float axv = 0.0f;
            if (q == 0 && j < 4) {
                axv = (j < 3) ? s * W_ih[g * 3 + j] : s * (b_ih[g] + b_hh[g]);
            }
            ax[j] = (short)f2bf(axv);
        }
        A_hh[G] = a;
        A_x[G]  = ax;
    }

    const long bn = (long)group * 16 + n;
    const float4* xv = (const float4*)(x + bn * (512L * 3));

    float cs[4] = {0.f, 0.f, 0.f, 0.f};
    float h[4]  = {0.f, 0.f, 0.f, 0.f};
    uint2 oth   = make_uint2(0u, 0u);

    float4 xa = xv[0], xb = xv[1], xc = xv[2];

    // prologue: accA = xproj(0)  (+ A_own*h(-1) = 0)
    f32x4 accA[4];
    {
        unsigned bx01 = pk_bf16(xa.x, xa.y);
        unsigned bx23 = pk_bf16(xa.z, 1.0f);
        u32x4 bxv = {bx01, bx23, bx01, bx23};
        bf16x8 Bx = __builtin_bit_cast(bf16x8, bxv);
#pragma unroll
        for (int G = 0; G < 4; ++G) {
            f32x4 z = {0.f, 0.f, 0.f, 0.f};
            accA[G] = MFMA(A_x[G], Bx, z);
        }
    }

// STEP(BUF, XN0..2): consumes accA (= xproj(t) + own-half h(t-1) contribution)
// and oth (partner h(t-1), read at tail of previous step).
#define STEP(BUF, XN0, XN1, XN2)                                                \
    do {                                                                        \
        /* x-projection for t+1 — independent of the pending oth read */        \
        unsigned bx01 = pk_bf16((XN0), (XN1));                                  \
        unsigned bx23 = pk_bf16((XN2), 1.0f);                                   \
        u32x4 bxv = {bx01, bx23, bx01, bx23};                                   \
        bf16x8 Bx = __builtin_bit_cast(bf16x8, bxv);                            \
        f32x4 accx[4];                                                          \
        _Pragma("unroll")                                                       \
        for (int G = 0; G < 4; ++G) {                                           \
            f32x4 z = {0.f, 0.f, 0.f, 0.f};                                     \
            accx[G] = MFMA(A_x[G], Bx, z);                                      \
        }                                                                       \
        /* finish gates(t): partner-half contribution */                        \
        u32x4 bov = {0u, 0u, oth.x, oth.y};                                     \
        bf16x8 Bo = __builtin_bit_cast(bf16x8, bov);                            \
        f32x4 acc[4];                                                           \
        _Pragma("unroll")                                                       \
        for (int G = 0; G < 4; ++G) acc[G] = MFMA(A_hh[G], Bo, accA[G]);        \
        /* cell math for 4 own units */                                         \
        _Pragma("unroll")                                                       \
        for (int r = 0; r < 4; ++r) {                                           \
            float ei = __builtin_amdgcn_exp2f(acc[0][r]);                       \
            float ef = __builtin_amdgcn_exp2f(acc[1][r]);                       \
            float eg = __builtin_amdgcn_exp2f(acc[2][r]);                       \
            float eo = __builtin_amdgcn_exp2f(acc[3][r]);                       \
            float a1 = 1.0f + ei, b1 = 1.0f + ef;                               \
            float c1 = 1.0f + eg, d1 = 1.0f + eo;                               \
            float rp = __builtin_amdgcn_rcpf(a1 * b1);                          \
            float rq = __builtin_amdgcn_rcpf(c1 * d1);                          \
            float ig = b1 * rp, fg = a1 * rp;                                   \
            float rg = d1 * rq, og = c1 * rq;                                   \
            float gp = fmaf(-5.7707801635558536f, rg, P2L2E);                   \
            cs[r] = fmaf(fg, cs[r], ig * gp);                                   \
            float ec = __builtin_amdgcn_exp2f(cs[r]);                           \
            float tc = fmaf(-2.0f, __builtin_amdgcn_rcpf(1.0f + ec), 1.0f);     \
            h[r] = og * tc;                                                     \
        }                                                                       \
        /* pack own half; start gates(t+1) own-half MFMA pre-barrier */         \
        uint2 own;                                                              \
        own.x = pk_bf16(h[0], h[1]);                                            \
        own.y = pk_bf16(h[2], h[3]);                                            \
        u32x4 bwv = {own.x, own.y, 0u, 0u};                                     \
        bf16x8 Bw = __builtin_bit_cast(bf16x8, bwv);                            \
        _Pragma("unroll")                                                       \
        for (int G = 0; G < 4; ++G) accA[G] = MFMA(A_hh[G], Bw, accx[G]);       \
        hx[BUF][w][lane] = own;                                                 \
        __syncthreads();                                                        \
        oth = hx[BUF][ow][lane];                                                \
    } while (0)

    for (int w4 = 0; w4 < 128; ++w4) {
        const int nw = (w4 < 127) ? (w4 + 1) : 127;
        float4 na = xv[3 * nw + 0];
        float4 nb = xv[3 * nw + 1];
        float4 nc = xv[3 * nw + 2];

        STEP(0, xa.w, xb.x, xb.y);
        STEP(1, xb.z, xb.w, xc.x);
        STEP(0, xc.y, xc.z, xc.w);
        STEP(1, na.x, na.y, na.z);

        xa = na; xb = nb; xc = nc;
    }
#undef STEP

    // FC + sigmoid (reduce over q via shuffles, over wave halves via LDS)
    float part = 0.f;
#pragma unroll
    for (int r = 0; r < 4; ++r) {
        part += W_fc[16 * w + 4 * q + r] * h[r];
    }
    part += __shfl_xor(part, 16, 64);
    part += __shfl_xor(part, 32, 64);
    if (q == 0) fcp[w][n] = part;
    __syncthreads();
    if (w == 0 && q == 0) {
        out[bn] = sigm(fcp[0][n] + fcp[1][n] + b_fc[0]);
    }
}

extern "C" void kernel_launch(void* const* d_in, const int* in_sizes, int n_in,
                              void* d_out, int out_size, void* d_ws, size_t ws_size,
                              hipStream_t stream) {
    const float* x    = (const float*)d_in[0];
    const float* W_ih = (const float*)d_in[1];
    const float* W_hh = (const float*)d_in[2];
    const float* b_ih = (const float*)d_in[3];
    const float* b_hh = (const float*)d_in[4];
    const float* W_fc = (const float*)d_in[5];
    const float* b_fc = (const float*)d_in[6];
    float* out        = (float*)d_out;

    const int n_groups = out_size / 16;   // 1024 groups, 2 waves each -> 2048 waves
    hipLaunchKernelGGL(lstm_mfma6_kernel, dim3(n_groups), dim3(128), 0, stream,
                       x, W_ih, W_hh, b_ih, b_hh, W_fc, b_fc, out);
}